// Round 14
// baseline (42.009 us; speedup 1.0000x reference)
//
#include <hip/hip_runtime.h>

typedef __attribute__((ext_vector_type(8)))  short short8;
typedef __attribute__((ext_vector_type(16))) float f32x16;

#define BATCH 8
#define NPTS  4096
#define NGRP  16              // target row-groups (256 rows each)
#define HALF  2048            // queries staged per LDS half
#define TPB1  512             // 8 waves: each owns a 32-row target strip
#define NSLICE NGRP
#define ONEB  0x3F80u         // bf16(1.0)
#define BIASB 0x4080u         // bf16(4.0)
#define BIASF 4.0f

// round-to-nearest-even f32 -> bf16 bits
__device__ __forceinline__ unsigned bfr(float f) {
    unsigned u = __float_as_uint(f);
    return (u + 0x7FFFu + ((u >> 16) & 1u)) >> 16;
}
__device__ __forceinline__ float ubf(unsigned s) {
    return __uint_as_float(s << 16);
}

// Stage 1 (MFMA): grid = 2 dirs x 8 batches x 16 target-rowgroups.
// Each wave owns 32 target rows (A-side frags, hi+lo split bf16, rt and the
// +BIAS folded into k-slots). Queries are staged in LDS as B-side frags
// (2048 at a time, 64 KB + 16 KB mincol = 80 KB). Per 32x32 tile: 2 chained
// mfma_f32_32x32x16_bf16 give P = |t-q|^2 + BIAS in f32 acc; col-min =
// 15-fmin tree + shfl_xor(32); combined across waves/tiles via LDS
// atomicMin on positive-float bits. Per-block result -> part[db][grp][q].
__global__ __launch_bounds__(TPB1, 2) void chamfer_mfma(
    const float* __restrict__ preds,
    const float* __restrict__ gts,
    float* __restrict__ part,   // [16 db][NGRP][NPTS]
    float* __restrict__ out)
{
    const int blk = blockIdx.x;
    const int grp = blk & 15;
    const int db  = blk >> 4;        // dir*8 + b
    const int dir = db >> 3;
    const int b   = db & 7;

    if (blk == 0 && threadIdx.x == 0) out[0] = 0.0f;

    // dir 0: output indexed by preds (queries=preds), min over gts (targets)
    const float* Q = dir ? gts   : preds;
    const float* T = dir ? preds : gts;

    __shared__ uint4    sB1[HALF];       // 32 KiB
    __shared__ uint4    sB2[HALF];       // 32 KiB
    __shared__ unsigned mincol[NPTS];    // 16 KiB

    for (int i = threadIdx.x; i < NPTS; i += TPB1)
        mincol[i] = 0x7F800000u;         // +inf bits (all stored values finite)

    const int lane = threadIdx.x & 63;
    const int wid  = threadIdx.x >> 6;
    const int la   = lane & 31;

    // ---- A-side fragments: wave's 32 target rows in lanes<32 (k=0..7);
    // lanes>=32 carry k=8..15 -> zero.
    short8 a1 = {}, a2 = {};
    if (lane < 32) {
        const float* tp = T + ((size_t)b * NPTS + grp * 256 + wid * 32 + la) * 3;
        const float X = tp[0], Y = tp[1], Z = tp[2];
        const float px = -2.f * X, py = -2.f * Y, pz = -2.f * Z;
        const float rt = fmaf(X, X, fmaf(Y, Y, Z * Z));
        const unsigned pxh = bfr(px), pyh = bfr(py), pzh = bfr(pz);
        const unsigned pxl = bfr(px - ubf(pxh)), pyl = bfr(py - ubf(pyh)),
                       pzl = bfr(pz - ubf(pzh));
        const unsigned rth = bfr(rt), rtl = bfr(rt - ubf(rth));
        a1[0] = (short)pxh; a1[1] = (short)pyh; a1[2] = (short)pzh;
        a1[3] = (short)rth; a1[4] = (short)rtl;
        a1[5] = (short)ONEB; a1[6] = (short)ONEB; a1[7] = (short)ONEB;
        a2[0] = (short)pxl; a2[1] = (short)pyl; a2[2] = (short)pzl;
        a2[3] = (short)pxh; a2[4] = (short)pyh; a2[5] = (short)pzh;
    }

    const f32x16 zacc = {};   // hoisted zero accumulator (C operand)

    for (int h = 0; h < 2; ++h) {
        __syncthreads();      // previous-half tile reads done / init visible

        // ---- stage 2048 query fragments (coalesced float4 raw reads)
        {
            const float4* q4 = reinterpret_cast<const float4*>(
                Q + ((size_t)b * NPTS + h * HALF) * 3);
            const int t = threadIdx.x;
            const float4 f0 = q4[3 * t], f1 = q4[3 * t + 1], f2 = q4[3 * t + 2];
            const float qx[4] = {f0.x, f0.w, f1.z, f2.y};
            const float qy[4] = {f0.y, f1.x, f1.w, f2.z};
            const float qz[4] = {f0.z, f1.y, f2.x, f2.w};
            #pragma unroll
            for (int i = 0; i < 4; ++i) {
                const float X = qx[i], Y = qy[i], Z = qz[i];
                const float rq = fmaf(X, X, fmaf(Y, Y, Z * Z));
                const unsigned xh = bfr(X), yh = bfr(Y), zh = bfr(Z);
                const unsigned xl = bfr(X - ubf(xh)), yl = bfr(Y - ubf(yh)),
                               zl = bfr(Z - ubf(zh));
                const unsigned rqh = bfr(rq), rql = bfr(rq - ubf(rqh));
                // B1 = {qxh,qyh,qzh, 1, 1, rqh, rql, BIAS}
                sB1[4 * t + i] = make_uint4(xh | (yh << 16), zh | (ONEB << 16),
                                            ONEB | (rqh << 16), rql | (BIASB << 16));
                // B2 = {qxh,qyh,qzh, qxl,qyl,qzl, 0, 0}
                sB2[4 * t + i] = make_uint4(xh | (yh << 16), zh | (xl << 16),
                                            yl | (zl << 16), 0u);
            }
        }
        __syncthreads();

        // ---- 64 col-block tiles, wave-skewed start to avoid atomic clashes
        for (int tt = 0; tt < HALF / 32; ++tt) {
            const int cb = (wid * 8 + tt) & (HALF / 32 - 1);
            short8 b1 = {}, b2 = {};
            if (lane < 32) {
                b1 = __builtin_bit_cast(short8, sB1[cb * 32 + la]);
                b2 = __builtin_bit_cast(short8, sB2[cb * 32 + la]);
            }
            f32x16 acc = __builtin_amdgcn_mfma_f32_32x32x16_bf16(a1, b1, zacc, 0, 0, 0);
            acc = __builtin_amdgcn_mfma_f32_32x32x16_bf16(a2, b2, acc, 0, 0, 0);

            // col-min: 16 rows per lane locally, then cross-half via xor 32
            const float m01 = fminf(acc[0], acc[1]),  m23 = fminf(acc[2], acc[3]);
            const float m45 = fminf(acc[4], acc[5]),  m67 = fminf(acc[6], acc[7]);
            const float m89 = fminf(acc[8], acc[9]),  mab = fminf(acc[10], acc[11]);
            const float mcd = fminf(acc[12], acc[13]), mef = fminf(acc[14], acc[15]);
            float m = fminf(fminf(fminf(m01, m23), fminf(m45, m67)),
                            fminf(fminf(m89, mab), fminf(mcd, mef)));
            m = fminf(m, __shfl_xor(m, 32, 64));
            if (lane < 32)
                atomicMin(&mincol[h * HALF + cb * 32 + la], __float_as_uint(m));
        }
    }
    __syncthreads();

    // ---- write this block's per-query partial mins (positive floats)
    float* dst = part + ((size_t)db * NGRP + grp) * NPTS;
    for (int i = threadIdx.x; i < NPTS; i += TPB1)
        dst[i] = __uint_as_float(mincol[i]);
}

// Stage 2: one thread per query; min over 16 rowgroup-partials, subtract
// BIAS, block-reduce, one atomicAdd per block.
#define TPB2 256
__global__ __launch_bounds__(TPB2) void chamfer_stage2(
    const float* __restrict__ part,
    float* __restrict__ out)
{
    const int g  = blockIdx.x * TPB2 + threadIdx.x;   // [0, 2*8*4096)
    const int db = g >> 12;
    const int q  = g & (NPTS - 1);

    const float* pp = part + (size_t)db * NSLICE * NPTS + q;
    float m = 3.4e38f;
    #pragma unroll
    for (int s = 0; s < NSLICE; ++s)
        m = fminf(m, pp[(size_t)s * NPTS]);

    float s = m - BIASF;

    #pragma unroll
    for (int off = 32; off > 0; off >>= 1)
        s += __shfl_down(s, off, 64);

    __shared__ float red[TPB2 / 64];
    const int lane = threadIdx.x & 63;
    const int wid  = threadIdx.x >> 6;
    if (lane == 0) red[wid] = s;
    __syncthreads();
    if (threadIdx.x == 0) {
        float t = 0.0f;
        #pragma unroll
        for (int w = 0; w < TPB2 / 64; ++w) t += red[w];
        atomicAdd(out, t);
    }
}

extern "C" void kernel_launch(void* const* d_in, const int* in_sizes, int n_in,
                              void* d_out, int out_size, void* d_ws, size_t ws_size,
                              hipStream_t stream) {
    const float* preds = (const float*)d_in[0];
    const float* gts   = (const float*)d_in[1];
    float* out  = (float*)d_out;
    float* part = (float*)d_ws;   // 16 db x 16 grps x 4096 floats = 4 MiB

    // 2 dispatches: stage1 zeroes `out`; part fully written before stage2.
    chamfer_mfma<<<dim3(2 * BATCH * NGRP), TPB1, 0, stream>>>(preds, gts, part, out);
    chamfer_stage2<<<dim3(2 * BATCH * NPTS / TPB2), TPB2, 0, stream>>>(part, out);
}

// Round 15
// 22.379 us; speedup vs baseline: 1.8772x; 1.8772x over previous
//
#include <hip/hip_runtime.h>

typedef __attribute__((ext_vector_type(8)))  short short8;
typedef __attribute__((ext_vector_type(16))) float f32x16;

#define BATCH 8
#define NPTS  4096
#define TPB   512             // 8 waves; each wave owns 32 query columns
#define NQG   16              // query groups of 256 per (dir,b)
#define ONEB  0x3F80u         // bf16(1.0)
#define BIASB 0x4080u         // bf16(4.0)
#define BIASF 4.0f

// round-to-nearest-even f32 -> bf16 bits
__device__ __forceinline__ unsigned bfr(float f) {
    unsigned u = __float_as_uint(f);
    return (u + 0x7FFFu + ((u >> 16) & 1u)) >> 16;
}
__device__ __forceinline__ float ubf(unsigned s) {
    return __uint_as_float(s << 16);
}

// One-kernel MFMA chamfer. Grid = 2 dirs x 8 batches x 16 query-groups.
// Encoding (verified absmax 0.0 in r14): P[r][c] = |t_r - q_c|^2 + BIAS via
// K=16 rank factorization, hi-terms in k0-7 (lanes<32), lo-terms in k8-15
// (lanes>=32) -> ONE v_mfma_f32_32x32x16_bf16 per 32x32 tile.
//   A row r: k0-7={-2t_h, rt_h, rt_l, 1,1,1}  k8-15={-2t_l, -2t_h, 0,0}
//   B col c: k0-7={q_h, 1, 1, rq_h, rq_l, BIAS} k8-15={q_h, q_l, 0, 0}
// Wave holds its 32 queries' B-frag in registers (built once); loops over
// 128 target tiles (A-frags from LDS, stride-16B conflict-free), reducing
// with entrywise v_min3_f32 into 16 register accumulators — no per-tile
// tree/shuffle/atomic (r14's killer). Block covers ALL targets for its 256
// queries => final min; epilogue: 8-op min tree + xor32 + block sum + one
// atomicAdd. No part buffer, no stage-2 kernel.
__global__ __launch_bounds__(TPB) void chamfer_mfma(
    const float* __restrict__ preds,
    const float* __restrict__ gts,
    float* __restrict__ out)
{
    const int blk = blockIdx.x;
    const int qg  = blk & 15;
    const int db  = blk >> 4;        // dir*8 + b
    const int dir = db >> 3;
    const int b   = db & 7;

    const float* Q = dir ? gts   : preds;   // query set (output-indexed)
    const float* T = dir ? preds : gts;     // target set (min'd over)

    __shared__ uint4 sA[2 * NPTS];   // [half][row] A-frags, 128 KiB
    __shared__ float red[TPB / 64];

    const size_t bbase = (size_t)b * NPTS;
    const int lane = threadIdx.x & 63;
    const int wid  = threadIdx.x >> 6;
    const int la   = lane & 31;
    const int h    = lane >> 5;

    // ---- stage all 4096 target rows as A-frags (rows thread-strided so
    // ds_writes are lane-consecutive 16B -> conflict-free)
    for (int j = 0; j < 8; ++j) {
        const int r = threadIdx.x + j * TPB;
        const float* tp = T + (bbase + r) * 3;
        const float X = tp[0], Y = tp[1], Z = tp[2];
        const float px = -2.f * X, py = -2.f * Y, pz = -2.f * Z;
        const float rt = fmaf(X, X, fmaf(Y, Y, Z * Z));
        const unsigned pxh = bfr(px), pyh = bfr(py), pzh = bfr(pz);
        const unsigned pxl = bfr(px - ubf(pxh)), pyl = bfr(py - ubf(pyh)),
                       pzl = bfr(pz - ubf(pzh));
        const unsigned rth = bfr(rt), rtl = bfr(rt - ubf(rth));
        sA[r]        = make_uint4(pxh | (pyh << 16), pzh | (rth << 16),
                                  rtl | (ONEB << 16), ONEB | (ONEB << 16));
        sA[NPTS + r] = make_uint4(pxl | (pyl << 16), pzl | (pxh << 16),
                                  pyh | (pzh << 16), 0u);
    }

    // ---- this lane's B-frag: query col c, half h (k0-7 vs k8-15)
    short8 bfrag;
    {
        const int c = qg * 256 + wid * 32 + la;
        const float* qp = Q + (bbase + c) * 3;
        const float X = qp[0], Y = qp[1], Z = qp[2];
        const float rq = fmaf(X, X, fmaf(Y, Y, Z * Z));
        const unsigned xh = bfr(X), yh = bfr(Y), zh = bfr(Z);
        const unsigned xl = bfr(X - ubf(xh)), yl = bfr(Y - ubf(yh)),
                       zl = bfr(Z - ubf(zh));
        const unsigned rqh = bfr(rq), rql = bfr(rq - ubf(rqh));
        const uint4 b1 = make_uint4(xh | (yh << 16), zh | (ONEB << 16),
                                    ONEB | (rqh << 16), rql | (BIASB << 16));
        const uint4 b2 = make_uint4(xh | (yh << 16), zh | (xl << 16),
                                    yl | (zl << 16), 0u);
        bfrag = __builtin_bit_cast(short8, h ? b2 : b1);
    }

    __syncthreads();

    // ---- main loop: 128 target tiles, 2 per iter, register min3 reduce
    const f32x16 zacc = {};
    f32x16 macc;
    #pragma unroll
    for (int i = 0; i < 16; ++i) macc[i] = 3.4e38f;

    const uint4* aBase = sA + h * NPTS + la;
    for (int t = 0; t < NPTS / 32; t += 2) {
        const uint4 A0 = aBase[t * 32];
        const uint4 A1 = aBase[t * 32 + 32];
        const f32x16 p0 = __builtin_amdgcn_mfma_f32_32x32x16_bf16(
            __builtin_bit_cast(short8, A0), bfrag, zacc, 0, 0, 0);
        const f32x16 p1 = __builtin_amdgcn_mfma_f32_32x32x16_bf16(
            __builtin_bit_cast(short8, A1), bfrag, zacc, 0, 0, 0);
        #pragma unroll
        for (int i = 0; i < 16; ++i)
            macc[i] = fminf(fminf(p0[i], p1[i]), macc[i]);   // v_min3_f32
    }

    // ---- epilogue: min over the 16 row-slots, then the other lane-half
    const float g0 = fminf(fminf(macc[0],  macc[1]),  macc[2]);
    const float g1 = fminf(fminf(macc[3],  macc[4]),  macc[5]);
    const float g2 = fminf(fminf(macc[6],  macc[7]),  macc[8]);
    const float g3 = fminf(fminf(macc[9],  macc[10]), macc[11]);
    const float g4 = fminf(fminf(macc[12], macc[13]), macc[14]);
    float m = fminf(fminf(fminf(g0, g1), fminf(g2, g3)),
                    fminf(g4, macc[15]));
    m = fminf(m, __shfl_xor(m, 32, 64));

    // ---- sum the 32 col-mins of this wave, then across waves, one atomic
    float s = (lane < 32) ? (m - BIASF) : 0.0f;
    #pragma unroll
    for (int off = 16; off > 0; off >>= 1)
        s += __shfl_down(s, off, 64);

    if (lane == 0) red[wid] = s;
    __syncthreads();
    if (threadIdx.x == 0) {
        float tsum = 0.0f;
        #pragma unroll
        for (int w = 0; w < TPB / 64; ++w) tsum += red[w];
        atomicAdd(out, tsum);
    }
}

extern "C" void kernel_launch(void* const* d_in, const int* in_sizes, int n_in,
                              void* d_out, int out_size, void* d_ws, size_t ws_size,
                              hipStream_t stream) {
    const float* preds = (const float*)d_in[0];
    const float* gts   = (const float*)d_in[1];
    float* out = (float*)d_out;

    hipMemsetAsync(out, 0, sizeof(float), stream);
    chamfer_mfma<<<dim3(2 * BATCH * NQG), TPB, 0, stream>>>(preds, gts, out);
}